// Round 4
// baseline (321.094 us; speedup 1.0000x reference)
//
#include <hip/hip_runtime.h>
#include <math.h>

// Problem constants
#define B_SZ 2
#define SEQ 512
#define DM 1024
#define DI 2048
#define DS 32
#define TOK (B_SZ*SEQ)        // 1024
#define NCH 8                 // scan chunks
#define CLEN (SEQ/NCH)        // 64
#define NG (CLEN/4)           // 16 float4 groups per chunk
#define NPAIR (B_SZ*DI*16)    // 65536 (d, rope-pair) lanes

// fused weight layout (rows of K=1024, bf16):
//   [0,4096) W_in | [4096,6144) W_dt | [6144,6176) W_B | [6176,6208) W_C | [6208,6272) pad
#define NFUSED 6272

__device__ __forceinline__ unsigned short f2bf(float f) {
  unsigned int u = __builtin_bit_cast(unsigned int, f);
  unsigned int r = u + 0x7fffu + ((u >> 16) & 1u);   // RNE (inputs finite)
  return (unsigned short)(r >> 16);
}

// ---------------- fused fp32 -> bf16 cast of all 6 tensors, 8 elems/thread ----------------
// group bounds (8-elem groups): x 131072 | W_in 524288 | W_dt 262144 | W_B 4096 | W_C 4096 | W_out 262144
__global__ __launch_bounds__(256) void fused_cast(const float* __restrict__ x,
                                                  const float* __restrict__ W_in,
                                                  const float* __restrict__ W_dt,
                                                  const float* __restrict__ W_B,
                                                  const float* __restrict__ W_C,
                                                  const float* __restrict__ W_out,
                                                  unsigned short* __restrict__ xb,
                                                  unsigned short* __restrict__ wcat,
                                                  unsigned short* __restrict__ wob) {
  int g = blockIdx.x * 256 + threadIdx.x;
  const float* s; unsigned short* dd; int off;
  if      (g <  131072) { s = x;     dd = xb;             off = 0; }
  else if (g <  655360) { s = W_in;  dd = wcat;           off = 131072; }
  else if (g <  917504) { s = W_dt;  dd = wcat + 4194304; off = 655360; }
  else if (g <  921600) { s = W_B;   dd = wcat + 6291456; off = 917504; }
  else if (g <  925696) { s = W_C;   dd = wcat + 6324224; off = 921600; }
  else if (g < 1187840) { s = W_out; dd = wob;            off = 925696; }
  else return;
  int i = g - off;
  float4 a = ((const float4*)s)[i * 2];
  float4 b = ((const float4*)s)[i * 2 + 1];
  union { unsigned short us[8]; uint4 v; } o;
  o.us[0] = f2bf(a.x); o.us[1] = f2bf(a.y); o.us[2] = f2bf(a.z); o.us[3] = f2bf(a.w);
  o.us[4] = f2bf(b.x); o.us[5] = f2bf(b.y); o.us[6] = f2bf(b.z); o.us[7] = f2bf(b.w);
  ((uint4*)dd)[i] = o.v;
}

// ---------------- bf16 MFMA GEMM (C = A * B^T), m97-style ----------------
typedef __attribute__((ext_vector_type(8))) short  frag8;
typedef __attribute__((ext_vector_type(4))) float  facc4;

__device__ __forceinline__ void gload_lds16(const unsigned short* g, unsigned short* l) {
  __builtin_amdgcn_global_load_lds((const __attribute__((address_space(1))) unsigned int*)g,
                                   (__attribute__((address_space(3))) unsigned int*)l, 16, 0, 0);
}

__device__ __forceinline__ float softplusf(float v) {
  return (v > 20.f) ? v : log1pf(expf(v));
}

// ROUTE=true epilogue: n<2048 -> xT[n][m] (f4) | <4096 -> zb[m][n-2048] | <6144 -> dtT (softplus, f4)
//                      | <6176 -> bcT[n-6144][m] (f4) | <6208 -> bcT[n-6176+32][m] (f4) | else discard
template<int BMt, int BNt, bool ROUTE>
__global__ __launch_bounds__(256) void gemm_mfma(const unsigned short* __restrict__ A,
                                                 const unsigned short* __restrict__ Bw,
                                                 int K,
                                                 float* __restrict__ o_xT,
                                                 float* __restrict__ o_zb,
                                                 float* __restrict__ o_dtT,
                                                 float* __restrict__ o_bcT,
                                                 const float* __restrict__ b_dt,
                                                 const float* __restrict__ dt_bias,
                                                 float* __restrict__ o_c, int ldc) {
  constexpr int FM = BMt / 32, FN = BNt / 32;
  constexpr int IA = BMt / 64, IB = BNt / 64;
  __shared__ __align__(16) unsigned short As[BMt * 32];
  __shared__ __align__(16) unsigned short Bs[BNt * 32];
  const int tid = threadIdx.x;
  const int w = tid >> 6, lane = tid & 63;
  const int wm = w >> 1, wn = w & 1;
  const int m0 = blockIdx.y * BMt, n0 = blockIdx.x * BNt;
  const int r = lane & 15, q = lane >> 4;
  const int grow = lane >> 2, gk = (lane & 3) * 8;
  facc4 acc[FM][FN] = {};
  const unsigned short* Ag = A + (size_t)m0 * K + gk;
  const unsigned short* Bg = Bw + (size_t)n0 * K + gk;

  for (int k0 = 0; k0 < K; k0 += 32) {
#pragma unroll
    for (int i = 0; i < IA; ++i) {
      int ch = i * 4 + w;
      gload_lds16(Ag + (size_t)(ch * 16 + grow) * K + k0, &As[ch * 512]);
    }
#pragma unroll
    for (int i = 0; i < IB; ++i) {
      int ch = i * 4 + w;
      gload_lds16(Bg + (size_t)(ch * 16 + grow) * K + k0, &Bs[ch * 512]);
    }
    __syncthreads();
    frag8 af[FM], bf[FN];
#pragma unroll
    for (int i = 0; i < FM; ++i)
      af[i] = *(const frag8*)&As[(wm * (BMt / 2) + i * 16 + r) * 32 + q * 8];
#pragma unroll
    for (int jj = 0; jj < FN; ++jj)
      bf[jj] = *(const frag8*)&Bs[(wn * (BNt / 2) + jj * 16 + r) * 32 + q * 8];
#pragma unroll
    for (int i = 0; i < FM; ++i)
#pragma unroll
      for (int jj = 0; jj < FN; ++jj)
        acc[i][jj] = __builtin_amdgcn_mfma_f32_16x16x32_bf16(af[i], bf[jj], acc[i][jj], 0, 0, 0);
    __syncthreads();
  }

#pragma unroll
  for (int i = 0; i < FM; ++i) {
#pragma unroll
    for (int jj = 0; jj < FN; ++jj) {
      int n = n0 + wn * (BNt / 2) + jj * 16 + r;
      int mb = m0 + wm * (BMt / 2) + i * 16 + q * 4;
      if (ROUTE) {
        if (n < 2048) {
          float4 v = make_float4(acc[i][jj][0], acc[i][jj][1], acc[i][jj][2], acc[i][jj][3]);
          *(float4*)&o_xT[(size_t)n * TOK + mb] = v;
        } else if (n < 4096) {
#pragma unroll
          for (int rg = 0; rg < 4; ++rg)
            o_zb[(size_t)(mb + rg) * DI + (n - 2048)] = acc[i][jj][rg];
        } else if (n < 6144) {
          int d = n - 4096;
          float bias = b_dt[d] + dt_bias[d];
          float4 v = make_float4(softplusf(acc[i][jj][0] + bias), softplusf(acc[i][jj][1] + bias),
                                 softplusf(acc[i][jj][2] + bias), softplusf(acc[i][jj][3] + bias));
          *(float4*)&o_dtT[(size_t)d * TOK + mb] = v;
        } else if (n < 6176) {
          float4 v = make_float4(acc[i][jj][0], acc[i][jj][1], acc[i][jj][2], acc[i][jj][3]);
          *(float4*)&o_bcT[(size_t)(n - 6144) * TOK + mb] = v;
        } else if (n < 6208) {
          float4 v = make_float4(acc[i][jj][0], acc[i][jj][1], acc[i][jj][2], acc[i][jj][3]);
          *(float4*)&o_bcT[(size_t)(n - 6176 + 32) * TOK + mb] = v;
        }
      } else {
#pragma unroll
        for (int rg = 0; rg < 4; ++rg)
          o_c[(size_t)(mb + rg) * ldc + n] = acc[i][jj][rg];
      }
    }
  }
}

// ---------------- chunked scan, transposed operands, float4 group loads ----------------
__global__ __launch_bounds__(256) void scan_p1(const float* __restrict__ xT,
                                               const float* __restrict__ dtT,
                                               const float* __restrict__ bcT,
                                               const float* __restrict__ A_log,
                                               const float* __restrict__ rope,
                                               float* __restrict__ Pbuf) {
  const int blk = blockIdx.x;
  const int c = blk >> 8;
  const int sub = blk & 255;
  const int b = sub >> 7;
  const int dbase = (sub & 127) << 4;
  const int dl = threadIdx.x >> 4;
  const int j = threadIdx.x & 15;
  const int d = dbase + dl;
  const int l0 = c * CLEN;
  const int tok0 = b * SEQ + l0;

  const float Ar_h = -0.5f * expf(A_log[d * DS + j]);
  const float Ai_h = -0.5f * expf(A_log[d * DS + j + 16]);
  const float fr = rope[j];
  float sn, cs, sF, cF;
  sincosf((float)l0 * fr, &sn, &cs);
  sincosf(fr, &sF, &cF);

  const float4* dtp = (const float4*)(dtT + (size_t)d * TOK + tok0);
  const float4* xp  = (const float4*)(xT  + (size_t)d * TOK + tok0);
  const float4* Brp = (const float4*)(bcT + (size_t)j * TOK + tok0);
  const float4* Bip = (const float4*)(bcT + (size_t)(j + 16) * TOK + tok0);

  float p00 = 1.f, p01 = 0.f, p10 = 0.f, p11 = 1.f;
  float ur = 0.f, ui = 0.f;
  float4 vdt = dtp[0], vx = xp[0], vBr = Brp[0], vBi = Bip[0];

  for (int g = 0; g < NG; ++g) {
    int gn = (g + 1 < NG) ? g + 1 : NG - 1;
    float4 ndt = dtp[gn], nx = xp[gn], nBr = Brp[gn], nBi = Bip[gn];
#pragma unroll
    for (int t = 0; t < 4; ++t) {
      float dtd = ((const float*)&vdt)[t];
      float xin = ((const float*)&vx)[t];
      float Br  = ((const float*)&vBr)[t];
      float Bi  = ((const float*)&vBi)[t];
      float hr = dtd * Ar_h, hi = dtd * Ai_h;
      float invr = __fdividef(1.f, 1.f - hr);
      float invi = __fdividef(1.f, 1.f - hi);
      float Abr = (1.f + hr) * invr;
      float Abi = (1.f + hi) * invi;
      float dx = dtd * xin;
      float bxr = dx * invr * Br;
      float bxi = dx * invi * Bi;
      float tr = fmaf(Abr, ur, bxr);
      float ti = fmaf(Abi, ui, bxi);
      ur = tr * cs - ti * sn;
      ui = tr * sn + ti * cs;
      float q00 = Abr * p00, q01 = Abr * p01;
      float q10 = Abi * p10, q11 = Abi * p11;
      p00 = q00 * cs - q10 * sn; p10 = q00 * sn + q10 * cs;
      p01 = q01 * cs - q11 * sn; p11 = q01 * sn + q11 * cs;
      float nc = cs * cF - sn * sF;
      float ns = sn * cF + cs * sF;
      cs = nc; sn = ns;
    }
    vdt = ndt; vx = nx; vBr = nBr; vBi = nBi;
  }
  const int pair = (b * DI + d) * 16 + j;
  Pbuf[(c * 6 + 0) * NPAIR + pair] = p00;
  Pbuf[(c * 6 + 1) * NPAIR + pair] = p01;
  Pbuf[(c * 6 + 2) * NPAIR + pair] = p10;
  Pbuf[(c * 6 + 3) * NPAIR + pair] = p11;
  Pbuf[(c * 6 + 4) * NPAIR + pair] = ur;
  Pbuf[(c * 6 + 5) * NPAIR + pair] = ui;
}

__global__ __launch_bounds__(256) void scan_p2(const float* __restrict__ Pbuf,
                                               float* __restrict__ Sbuf) {
  int pair = blockIdx.x * 256 + threadIdx.x;
  float sr = 0.f, si = 0.f;
#pragma unroll
  for (int c = 0; c < NCH; ++c) {
    Sbuf[(c * 2 + 0) * NPAIR + pair] = sr;
    Sbuf[(c * 2 + 1) * NPAIR + pair] = si;
    float p00 = Pbuf[(c * 6 + 0) * NPAIR + pair];
    float p01 = Pbuf[(c * 6 + 1) * NPAIR + pair];
    float p10 = Pbuf[(c * 6 + 2) * NPAIR + pair];
    float p11 = Pbuf[(c * 6 + 3) * NPAIR + pair];
    float ur  = Pbuf[(c * 6 + 4) * NPAIR + pair];
    float ui  = Pbuf[(c * 6 + 5) * NPAIR + pair];
    float nr = p00 * sr + p01 * si + ur;
    float ni = p10 * sr + p11 * si + ui;
    sr = nr; si = ni;
  }
}

__global__ __launch_bounds__(256) void scan_p3(const float* __restrict__ xT,
                                               const float* __restrict__ dtT,
                                               const float* __restrict__ bcT,
                                               const float* __restrict__ A_log,
                                               const float* __restrict__ rope,
                                               const float* __restrict__ Sbuf,
                                               float* __restrict__ y,
                                               float* __restrict__ fstate) {
  const int blk = blockIdx.x;
  const int c = blk >> 8;
  const int sub = blk & 255;
  const int b = sub >> 7;
  const int dbase = (sub & 127) << 4;
  const int dl = threadIdx.x >> 4;
  const int j = threadIdx.x & 15;
  const int d = dbase + dl;
  const int l0 = c * CLEN;
  const int tok0 = b * SEQ + l0;

  const float Ar_h = -0.5f * expf(A_log[d * DS + j]);
  const float Ai_h = -0.5f * expf(A_log[d * DS + j + 16]);
  const float fr = rope[j];
  float sn, cs, sF, cF;
  sincosf((float)l0 * fr, &sn, &cs);
  sincosf(fr, &sF, &cF);

  const float4* dtp = (const float4*)(dtT + (size_t)d * TOK + tok0);
  const float4* xp  = (const float4*)(xT  + (size_t)d * TOK + tok0);
  const float4* Brp = (const float4*)(bcT + (size_t)j * TOK + tok0);
  const float4* Bip = (const float4*)(bcT + (size_t)(j + 16) * TOK + tok0);
  const float4* Crp = (const float4*)(bcT + (size_t)(j + 32) * TOK + tok0);
  const float4* Cip = (const float4*)(bcT + (size_t)(j + 48) * TOK + tok0);
  float* yp = y + (size_t)tok0 * DI + d;

  const int pair = (b * DI + d) * 16 + j;
  float sr = Sbuf[(c * 2 + 0) * NPAIR + pair];
  float si = Sbuf[(c * 2 + 1) * NPAIR + pair];

  float4 vdt = dtp[0], vx = xp[0], vBr = Brp[0], vBi = Bip[0], vCr = Crp[0], vCi = Cip[0];

  for (int g = 0; g < NG; ++g) {
    int gn = (g + 1 < NG) ? g + 1 : NG - 1;
    float4 ndt = dtp[gn], nx = xp[gn], nBr = Brp[gn], nBi = Bip[gn], nCr = Crp[gn], nCi = Cip[gn];
#pragma unroll
    for (int t = 0; t < 4; ++t) {
      float dtd = ((const float*)&vdt)[t];
      float xin = ((const float*)&vx)[t];
      float Br  = ((const float*)&vBr)[t];
      float Bi  = ((const float*)&vBi)[t];
      float Cr  = ((const float*)&vCr)[t];
      float Ci  = ((const float*)&vCi)[t];
      float hr = dtd * Ar_h, hi = dtd * Ai_h;
      float invr = __fdividef(1.f, 1.f - hr);
      float invi = __fdividef(1.f, 1.f - hi);
      float Abr = (1.f + hr) * invr;
      float Abi = (1.f + hi) * invi;
      float dx = dtd * xin;
      float bxr = dx * invr * Br;
      float bxi = dx * invi * Bi;
      float tr = fmaf(Abr, sr, bxr);
      float ti = fmaf(Abi, si, bxi);
      sr = tr * cs - ti * sn;
      si = tr * sn + ti * cs;
      float p = sr * Cr + si * Ci;
      p += __shfl_xor(p, 8);
      p += __shfl_xor(p, 4);
      p += __shfl_xor(p, 2);
      p += __shfl_xor(p, 1);
      if (j == 0) yp[(g * 4 + t) * DI] = p;
      float nc = cs * cF - sn * sF;
      float ns = sn * cF + cs * sF;
      cs = nc; sn = ns;
    }
    vdt = ndt; vx = nx; vBr = nBr; vBi = nBi; vCr = nCr; vCi = nCi;
  }
  if (c == NCH - 1) {
    fstate[((size_t)b * DI + d) * DS + j]      = sr;
    fstate[((size_t)b * DI + d) * DS + j + 16] = si;
  }
}

// ---------------- gate (y * silu(z)) + LayerNorm, bf16 output ----------------
__global__ __launch_bounds__(256) void gate_ln(const float* __restrict__ y,
                                               const float* __restrict__ zb,
                                               const float* __restrict__ lw,
                                               const float* __restrict__ lb,
                                               unsigned short* __restrict__ o) {
  int tok = blockIdx.x;
  int t = threadIdx.x;
  float g[8];
  float sum = 0.f, sq = 0.f;
#pragma unroll
  for (int i = 0; i < 8; ++i) {
    int dd = t + i * 256;
    float yv = y[(size_t)tok * DI + dd];
    float zv = zb[(size_t)tok * DI + dd];
    float sg = zv / (1.f + expf(-zv));
    float v = yv * sg;
    g[i] = v; sum += v; sq += v * v;
  }
#pragma unroll
  for (int off = 32; off; off >>= 1) { sum += __shfl_xor(sum, off); sq += __shfl_xor(sq, off); }
  __shared__ float rs[4], rq[4];
  int w = t >> 6;
  if ((t & 63) == 0) { rs[w] = sum; rq[w] = sq; }
  __syncthreads();
  sum = rs[0] + rs[1] + rs[2] + rs[3];
  sq  = rq[0] + rq[1] + rq[2] + rq[3];
  float mu = sum * (1.f / DI);
  float var = sq * (1.f / DI) - mu * mu;
  float rstd = rsqrtf(var + 1e-5f);
#pragma unroll
  for (int i = 0; i < 8; ++i) {
    int dd = t + i * 256;
    o[(size_t)tok * DI + dd] = f2bf((g[i] - mu) * rstd * lw[dd] + lb[dd]);
  }
}

// ---------------- launch ----------------
extern "C" void kernel_launch(void* const* d_in, const int* in_sizes, int n_in,
                              void* d_out, int out_size, void* d_ws, size_t ws_size,
                              hipStream_t stream) {
  const float* x       = (const float*)d_in[0];
  const float* W_in    = (const float*)d_in[1];
  const float* A_log   = (const float*)d_in[2];
  const float* W_B     = (const float*)d_in[3];
  const float* W_C     = (const float*)d_in[4];
  const float* W_dt    = (const float*)d_in[5];
  const float* b_dt    = (const float*)d_in[6];
  const float* dt_bias = (const float*)d_in[7];
  const float* rope    = (const float*)d_in[8];
  const float* ln_w    = (const float*)d_in[9];
  const float* ln_b    = (const float*)d_in[10];
  const float* W_out   = (const float*)d_in[11];
  float* out = (float*)d_out;
  float* ws = (float*)d_ws;

  // workspace layout (float offsets); overlays noted
  float* xT   = ws;                                   // [0, 2097152)
  float* zb   = ws + 2097152;                         // [2097152, 4194304)
  float* dtT  = ws + 4194304;                         // [4194304, 6291456)
  float* bcT  = ws + 6291456;                         // [6291456, 6356992)
  unsigned short* wob  = (unsigned short*)(ws + 6356992);  // 2M bf16   [.., 7405568)
  unsigned short* xb   = (unsigned short*)(ws + 7405568);  // 1M bf16   [.., 7929856)
  unsigned short* wcat = (unsigned short*)(ws + 7929856);  // 6.42M bf16 [.., 11141120)
  float* Pbuf = ws + 7929856;                         // 3145728 f, alias wcat (dead after GEMM)
  float* Sbuf = ws + 11141120;                        // 1048576 f  [.., 12189696)
  float* yb   = ws + 7929856;                         // 2097152 f, alias Pbuf (dead after p2)
  unsigned short* lnb = (unsigned short*)(ws + 10027008);  // 2M bf16, after yb, in dead Pbuf tail
  float* fstate = out + (size_t)TOK * DM;

  // 1) fused bf16 casts (x, W_in, W_dt, W_B, W_C, W_out)
  fused_cast<<<4640, 256, 0, stream>>>(x, W_in, W_dt, W_B, W_C, W_out, xb, wcat, wob);
  // 2) fused input GEMM: routes to xT / zb / dtT(softplus) / bcT
  gemm_mfma<128, 128, true><<<dim3(NFUSED / 128, TOK / 128), 256, 0, stream>>>(
      xb, wcat, DM, xT, zb, dtT, bcT, b_dt, dt_bias, nullptr, 0);
  // 3) chunked scan
  scan_p1<<<NCH * 256, 256, 0, stream>>>(xT, dtT, bcT, A_log, rope, Pbuf);
  scan_p2<<<NPAIR / 256, 256, 0, stream>>>(Pbuf, Sbuf);
  scan_p3<<<NCH * 256, 256, 0, stream>>>(xT, dtT, bcT, A_log, rope, Sbuf, yb, fstate);
  // 4) gate + LN (bf16 out)
  gate_ln<<<TOK, 256, 0, stream>>>(yb, zb, ln_w, ln_b, lnb);
  // 5) out = ln @ W_out^T
  gemm_mfma<64, 64, false><<<dim3(DM / 64, TOK / 64), 256, 0, stream>>>(
      lnb, wob, DI, nullptr, nullptr, nullptr, nullptr, nullptr, nullptr, out, DM);
}